// Round 2
// baseline (1249.527 us; speedup 1.0000x reference)
//
#include <hip/hip_runtime.h>
#include <hip/hip_fp16.h>
#include <math.h>

#define HID 64
#define HEADS 4
#define HC (HEADS * HID)   // 256
#define IN_DIM 32
#define NEG 0.2f
#define BN_EPS 1e-5f

// ---------- index dtype detection ----------
// If indices were materialized as int64 (little-endian, values in [0, 2^31)),
// every odd 32-bit word of edge_index is zero. 32 random node ids in
// [0, 50000) being all zero is impossible -> safe discriminator.
__global__ void k_detect64(const int* __restrict__ ei, int* __restrict__ flag) {
    if (blockIdx.x == 0 && threadIdx.x == 0) {
        int z = 1;
#pragma unroll
        for (int i = 1; i < 64; i += 2) z &= (ei[i] == 0);
        *flag = z;
    }
}

// flat element i of an int array that may be stored as int32 or int64
__device__ __forceinline__ int ld_idx(const int* __restrict__ p, int i, int f64) {
    return f64 ? p[(size_t)2 * i] : p[i];
}

__global__ void k_zero(float* __restrict__ p, int n) {
    int i = blockIdx.x * blockDim.x + threadIdx.x;
    if (i < n) p[i] = 0.f;
}

// ---------- h = x @ in_W + in_b   (x:[N,32], in_W:[32,64]) ----------
__global__ void k_input(const float* __restrict__ x, const float* __restrict__ W,
                        const float* __restrict__ b, float* __restrict__ h, int N) {
    int n = blockIdx.x;
    int c = threadIdx.x;  // 0..63
    __shared__ float xs[IN_DIM];
    if (c < IN_DIM) xs[c] = x[n * IN_DIM + c];
    __syncthreads();
    float acc = b[c];
#pragma unroll
    for (int k = 0; k < IN_DIM; ++k) acc += xs[k] * W[k * HID + c];
    h[(size_t)n * HID + c] = acc;
}

// ---------- per-layer: xt = h @ W (reshape [N,4,64]) + attention scores ----------
// 256 threads, NPB nodes per block. Each wave (64 lanes) = one head.
#define NPB 8
__global__ void k_gat_xt(const float* __restrict__ h, const float* __restrict__ W,
                         const float* __restrict__ asrc, const float* __restrict__ adst,
                         __half* __restrict__ xt, float* __restrict__ ssrc,
                         float* __restrict__ sdst, int N) {
    int t = threadIdx.x;           // 0..255
    int head = t >> 6, lane = t & 63;
    int n0 = blockIdx.x * NPB;
    __shared__ float hs[NPB][HID];
    for (int idx = t; idx < NPB * HID; idx += 256) {
        int j = idx / HID, k = idx % HID;
        int n = n0 + j;
        hs[j][k] = (n < N) ? h[(size_t)n * HID + k] : 0.f;
    }
    __syncthreads();
    float acc[NPB];
#pragma unroll
    for (int j = 0; j < NPB; ++j) acc[j] = 0.f;
    for (int k = 0; k < HID; ++k) {
        float w = W[k * HC + t];
#pragma unroll
        for (int j = 0; j < NPB; ++j) acc[j] += hs[j][k] * w;
    }
    float as = asrc[head * HID + lane];
    float ad = adst[head * HID + lane];
#pragma unroll
    for (int j = 0; j < NPB; ++j) {
        int n = n0 + j;
        if (n >= N) break;
        xt[(size_t)n * HC + t] = __float2half(acc[j]);
        float vs = acc[j] * as;
        float vd = acc[j] * ad;
#pragma unroll
        for (int m = 32; m >= 1; m >>= 1) {
            vs += __shfl_xor(vs, m, 64);
            vd += __shfl_xor(vd, m, 64);
        }
        if (lane == 0) {
            ssrc[(size_t)n * HEADS + head] = vs;
            sdst[(size_t)n * HEADS + head] = vd;
        }
    }
}

// ---------- softmax denominators (one thread per (edge,head)) ----------
__global__ void k_denom(const int* __restrict__ ei, const int* __restrict__ flagp,
                        const float* __restrict__ ssrc, const float* __restrict__ sdst,
                        float* __restrict__ denom, int E, int Etot) {
    int idx = blockIdx.x * blockDim.x + threadIdx.x;
    if (idx >= Etot * HEADS) return;
    const int f = *flagp;
    int e = idx >> 2, hh = idx & 3;
    int s, d;
    if (e < E) { s = ld_idx(ei, e, f); d = ld_idx(ei, E + e, f); }
    else       { s = d = e - E; }
    float v = ssrc[s * HEADS + hh] + sdst[d * HEADS + hh];
    v = v > 0.f ? v : NEG * v;
    atomicAdd(&denom[d * HEADS + hh], expf(v));
}

// ---------- message pass: one 64-lane wave per edge ----------
// aggr[d][c] += 0.25 * sum_h alpha_h * xt[s][h][c]
__global__ void k_msg(const int* __restrict__ ei, const int* __restrict__ flagp,
                      const float* __restrict__ ssrc, const float* __restrict__ sdst,
                      const float* __restrict__ denom, const __half* __restrict__ xt,
                      float* __restrict__ aggr, int E, int Etot) {
    int wid = (int)((blockIdx.x * (size_t)blockDim.x + threadIdx.x) >> 6);
    int lane = threadIdx.x & 63;
    if (wid >= Etot) return;
    const int f = *flagp;
    int s, d;
    if (wid < E) { s = ld_idx(ei, wid, f); d = ld_idx(ei, E + wid, f); }
    else         { s = d = wid - E; }
    float a = 0.f;
    if (lane < HEADS) {
        float v = ssrc[s * HEADS + lane] + sdst[d * HEADS + lane];
        v = v > 0.f ? v : NEG * v;
        a = expf(v) / (denom[d * HEADS + lane] + 1e-16f);
    }
    const __half* row = xt + (size_t)s * HC;
    float m = 0.f;
#pragma unroll
    for (int hh = 0; hh < HEADS; ++hh) {
        float ah = __shfl(a, hh, 64);
        m += ah * __half2float(row[hh * HID + lane]);
    }
    atomicAdd(&aggr[(size_t)d * HID + lane], 0.25f * m);
}

// ---------- node update: bias + BN(eval) + relu + residual ----------
__global__ void k_node_update(const float* __restrict__ aggr, const float* __restrict__ gb,
                              const float* __restrict__ bg, const float* __restrict__ bb,
                              const float* __restrict__ bm, const float* __restrict__ bv,
                              float* __restrict__ h, int N) {
    int i = blockIdx.x * blockDim.x + threadIdx.x;
    if (i >= N * HID) return;
    int c = i & (HID - 1);
    float v = aggr[i] + gb[c];
    v = (v - bm[c]) * rsqrtf(bv[c] + BN_EPS) * bg[c] + bb[c];
    v = fmaxf(v, 0.f);
    h[i] = v + h[i];
}

// ---------- global mean pool (batch sorted) ----------
__device__ __forceinline__ int lower_bound_i(const int* __restrict__ a, int n, int v, int f) {
    int lo = 0, hi = n;
    while (lo < hi) {
        int mid = (lo + hi) >> 1;
        if (ld_idx(a, mid, f) < v) lo = mid + 1; else hi = mid;
    }
    return lo;
}

__global__ void k_pool(const float* __restrict__ h, const int* __restrict__ batch,
                       const int* __restrict__ flagp, float* __restrict__ g, int N) {
    int gg = blockIdx.x, c = threadIdx.x;  // 64 threads
    const int f = *flagp;
    int lo = lower_bound_i(batch, N, gg, f);
    int hi = lower_bound_i(batch, N, gg + 1, f);
    float s = 0.f;
    for (int n = lo; n < hi; ++n) s += h[(size_t)n * HID + c];
    float cnt = (float)(hi - lo);
    g[gg * HID + c] = s / fmaxf(cnt, 1.f);
}

// ---------- final MLP head ----------
__global__ void k_mlp(const float* __restrict__ g, const float* __restrict__ W1,
                      const float* __restrict__ b1, const float* __restrict__ W2,
                      const float* __restrict__ b2, float* __restrict__ out, int OUTD) {
    int gg = blockIdx.x, c = threadIdx.x;  // 64 threads
    __shared__ float gs[HID];
    __shared__ float s1[HID];
    gs[c] = g[gg * HID + c];
    __syncthreads();
    float acc = b1[c];
#pragma unroll
    for (int k = 0; k < HID; ++k) acc += gs[k] * W1[k * HID + c];
    s1[c] = fmaxf(acc, 0.f);
    __syncthreads();
    if (c < OUTD) {
        float o = b2[c];
#pragma unroll
        for (int k = 0; k < HID; ++k) o += s1[k] * W2[k * OUTD + c];
        out[gg * OUTD + c] = o;
    }
}

extern "C" void kernel_launch(void* const* d_in, const int* in_sizes, int n_in,
                              void* d_out, int out_size, void* d_ws, size_t ws_size,
                              hipStream_t stream) {
    const float* x       = (const float*)d_in[0];
    const int*   ei_raw  = (const int*)d_in[1];
    const int*   b_raw   = (const int*)d_in[2];
    const float* in_W    = (const float*)d_in[3];
    const float* in_b    = (const float*)d_in[4];
    const float* gat_W   = (const float*)d_in[5];
    const float* att_src = (const float*)d_in[6];
    const float* att_dst = (const float*)d_in[7];
    const float* gat_b   = (const float*)d_in[8];
    const float* bn_g    = (const float*)d_in[9];
    const float* bn_b    = (const float*)d_in[10];
    const float* bn_m    = (const float*)d_in[11];
    const float* bn_v    = (const float*)d_in[12];
    const float* fc1_W   = (const float*)d_in[13];
    const float* fc1_b   = (const float*)d_in[14];
    const float* fc2_W   = (const float*)d_in[15];
    const float* fc2_b   = (const float*)d_in[16];

    const int N = in_sizes[2];          // n_nodes (batch length)
    const int E = in_sizes[1] / 2;      // edges
    const int Etot = E + N;             // + self loops
    const int OUTD = 4;
    const int G = out_size / OUTD;

    // workspace layout (floats), ~53.7 MB total for N=50k
    float* ws = (float*)d_ws;
    float* h     = ws;                           // N*64
    float* ssrc  = h    + (size_t)N * HID;       // N*4
    float* sdst  = ssrc + (size_t)N * HEADS;     // N*4
    float* denom = sdst + (size_t)N * HEADS;     // N*4
    float* aggr  = denom+ (size_t)N * HEADS;     // N*64 (contiguous with denom)
    float* gpool = aggr + (size_t)N * HID;       // G*64
    int*   flag  = (int*)(gpool + (size_t)G * HID); // 1
    __half* xt   = (__half*)(flag + 2);          // N*256 halves

    k_detect64<<<1, 64, 0, stream>>>(ei_raw, flag);

    k_input<<<N, HID, 0, stream>>>(x, in_W, in_b, h, N);

    for (int l = 0; l < 3; ++l) {
        k_gat_xt<<<(N + NPB - 1) / NPB, 256, 0, stream>>>(
            h, gat_W + (size_t)l * HID * HC, att_src + (size_t)l * HEADS * HID,
            att_dst + (size_t)l * HEADS * HID, xt, ssrc, sdst, N);
        int zn = N * HEADS + N * HID;  // denom + aggr (contiguous)
        k_zero<<<(zn + 255) / 256, 256, 0, stream>>>(denom, zn);
        k_denom<<<(Etot * HEADS + 255) / 256, 256, 0, stream>>>(ei_raw, flag, ssrc, sdst, denom, E, Etot);
        k_msg<<<(int)(((size_t)Etot * 64 + 255) / 256), 256, 0, stream>>>(
            ei_raw, flag, ssrc, sdst, denom, xt, aggr, E, Etot);
        k_node_update<<<(N * HID + 255) / 256, 256, 0, stream>>>(
            aggr, gat_b + (size_t)l * HID, bn_g + (size_t)l * HID, bn_b + (size_t)l * HID,
            bn_m + (size_t)l * HID, bn_v + (size_t)l * HID, h, N);
    }

    k_pool<<<G, HID, 0, stream>>>(h, b_raw, flag, gpool, N);
    k_mlp<<<G, HID, 0, stream>>>(gpool, fc1_W, fc1_b, fc2_W, fc2_b, (float*)d_out, OUTD);
}

// Round 3
// 1040.796 us; speedup vs baseline: 1.2005x; 1.2005x over previous
//
#include <hip/hip_runtime.h>
#include <hip/hip_fp16.h>
#include <math.h>

#define HID 64
#define HEADS 4
#define HC (HEADS * HID)   // 256
#define IN_DIM 32
#define NEG 0.2f
#define BN_EPS 1e-5f

// ---------- index dtype detection ----------
// If indices were materialized as int64 (little-endian, values in [0, 2^31)),
// every odd 32-bit word of edge_index is zero. 32 random node ids in
// [0, 50000) being all zero is impossible -> safe discriminator.
__global__ void k_detect64(const int* __restrict__ ei, int* __restrict__ flag) {
    if (blockIdx.x == 0 && threadIdx.x == 0) {
        int z = 1;
#pragma unroll
        for (int i = 1; i < 64; i += 2) z &= (ei[i] == 0);
        *flag = z;
    }
}

// flat element i of an int array that may be stored as int32 or int64
__device__ __forceinline__ int ld_idx(const int* __restrict__ p, int i, int f64) {
    return f64 ? p[(size_t)2 * i] : p[i];
}

__global__ void k_zero(float* __restrict__ p, int n) {
    int i = blockIdx.x * blockDim.x + threadIdx.x;
    if (i < n) p[i] = 0.f;
}

// ---------- h = x @ in_W + in_b   (x:[N,32], in_W:[32,64]) ----------
__global__ void k_input(const float* __restrict__ x, const float* __restrict__ W,
                        const float* __restrict__ b, float* __restrict__ h, int N) {
    int n = blockIdx.x;
    int c = threadIdx.x;  // 0..63
    __shared__ float xs[IN_DIM];
    if (c < IN_DIM) xs[c] = x[n * IN_DIM + c];
    __syncthreads();
    float acc = b[c];
#pragma unroll
    for (int k = 0; k < IN_DIM; ++k) acc += xs[k] * W[k * HID + c];
    h[(size_t)n * HID + c] = acc;
}

// ---------- per-layer: xt = h @ W (reshape [N,4,64]) + attention scores ----------
// 256 threads, NPB nodes per block. Each wave (64 lanes) = one head.
#define NPB 8
__global__ void k_gat_xt(const float* __restrict__ h, const float* __restrict__ W,
                         const float* __restrict__ asrc, const float* __restrict__ adst,
                         __half* __restrict__ xt, float* __restrict__ ssrc,
                         float* __restrict__ sdst, int N) {
    int t = threadIdx.x;           // 0..255
    int head = t >> 6, lane = t & 63;
    int n0 = blockIdx.x * NPB;
    __shared__ float hs[NPB][HID];
    for (int idx = t; idx < NPB * HID; idx += 256) {
        int j = idx / HID, k = idx % HID;
        int n = n0 + j;
        hs[j][k] = (n < N) ? h[(size_t)n * HID + k] : 0.f;
    }
    __syncthreads();
    float acc[NPB];
#pragma unroll
    for (int j = 0; j < NPB; ++j) acc[j] = 0.f;
    for (int k = 0; k < HID; ++k) {
        float w = W[k * HC + t];
#pragma unroll
        for (int j = 0; j < NPB; ++j) acc[j] += hs[j][k] * w;
    }
    float as = asrc[head * HID + lane];
    float ad = adst[head * HID + lane];
#pragma unroll
    for (int j = 0; j < NPB; ++j) {
        int n = n0 + j;
        if (n >= N) break;
        xt[(size_t)n * HC + t] = __float2half(acc[j]);
        float vs = acc[j] * as;
        float vd = acc[j] * ad;
#pragma unroll
        for (int m = 32; m >= 1; m >>= 1) {
            vs += __shfl_xor(vs, m, 64);
            vd += __shfl_xor(vd, m, 64);
        }
        if (lane == 0) {
            ssrc[(size_t)n * HEADS + head] = vs;
            sdst[(size_t)n * HEADS + head] = vd;
        }
    }
}

// ---------- softmax denominators (one thread per (edge,head)) ----------
__global__ void k_denom(const int* __restrict__ ei, const int* __restrict__ flagp,
                        const float* __restrict__ ssrc, const float* __restrict__ sdst,
                        float* __restrict__ denom, int E, int Etot) {
    int idx = blockIdx.x * blockDim.x + threadIdx.x;
    if (idx >= Etot * HEADS) return;
    const int f = *flagp;
    int e = idx >> 2, hh = idx & 3;
    int s, d;
    if (e < E) { s = ld_idx(ei, e, f); d = ld_idx(ei, E + e, f); }
    else       { s = d = e - E; }
    float v = ssrc[s * HEADS + hh] + sdst[d * HEADS + hh];
    v = v > 0.f ? v : NEG * v;
    atomicAdd(&denom[d * HEADS + hh], expf(v));
}

// ---------- message pass: one 64-lane wave per edge ----------
// aggr[d][c] += 0.25 * sum_h alpha_h * xt[s][h][c]
__global__ void k_msg(const int* __restrict__ ei, const int* __restrict__ flagp,
                      const float* __restrict__ ssrc, const float* __restrict__ sdst,
                      const float* __restrict__ denom, const __half* __restrict__ xt,
                      float* __restrict__ aggr, int E, int Etot) {
    int wid = (int)((blockIdx.x * (size_t)blockDim.x + threadIdx.x) >> 6);
    int lane = threadIdx.x & 63;
    if (wid >= Etot) return;
    const int f = *flagp;
    int s, d;
    if (wid < E) { s = ld_idx(ei, wid, f); d = ld_idx(ei, E + wid, f); }
    else         { s = d = wid - E; }
    float a = 0.f;
    if (lane < HEADS) {
        float v = ssrc[s * HEADS + lane] + sdst[d * HEADS + lane];
        v = v > 0.f ? v : NEG * v;
        a = expf(v) / (denom[d * HEADS + lane] + 1e-16f);
    }
    const __half* row = xt + (size_t)s * HC;
    float m = 0.f;
#pragma unroll
    for (int hh = 0; hh < HEADS; ++hh) {
        float ah = __shfl(a, hh, 64);
        m += ah * __half2float(row[hh * HID + lane]);
    }
    atomicAdd(&aggr[(size_t)d * HID + lane], 0.25f * m);
}

// ---------- node update: bias + BN(eval) + relu + residual ----------
__global__ void k_node_update(const float* __restrict__ aggr, const float* __restrict__ gb,
                              const float* __restrict__ bg, const float* __restrict__ bb,
                              const float* __restrict__ bm, const float* __restrict__ bv,
                              float* __restrict__ h, int N) {
    int i = blockIdx.x * blockDim.x + threadIdx.x;
    if (i >= N * HID) return;
    int c = i & (HID - 1);
    float v = aggr[i] + gb[c];
    v = (v - bm[c]) * rsqrtf(bv[c] + BN_EPS) * bg[c] + bb[c];
    v = fmaxf(v, 0.f);
    h[i] = v + h[i];
}

// ---------- global mean pool: node-parallel partial sums ----------
// One wave per NPBK contiguous nodes; lane = channel. batch is sorted, so a
// block spans at most a few graphs: keep a running sum, flush on boundary.
#define NPBK 64
__global__ void k_pool_sum(const float* __restrict__ h, const int* __restrict__ batch,
                           const int* __restrict__ flagp, float* __restrict__ gsum, int N) {
    const int f = *flagp;
    int c = threadIdx.x;  // 0..63
    int n0 = blockIdx.x * NPBK;
    int n1 = min(n0 + NPBK, N);
    if (n0 >= N) return;
    int cur = ld_idx(batch, n0, f);
    float s = 0.f;
    for (int n = n0; n < n1; ++n) {
        int g = ld_idx(batch, n, f);
        if (g != cur) {
            atomicAdd(&gsum[cur * HID + c], s);
            s = 0.f;
            cur = g;
        }
        s += h[(size_t)n * HID + c];
    }
    atomicAdd(&gsum[cur * HID + c], s);
}

__device__ __forceinline__ int lower_bound_i(const int* __restrict__ a, int n, int v, int f) {
    int lo = 0, hi = n;
    while (lo < hi) {
        int mid = (lo + hi) >> 1;
        if (ld_idx(a, mid, f) < v) lo = mid + 1; else hi = mid;
    }
    return lo;
}

// ---------- final MLP head (mean-divide fused in) ----------
__global__ void k_mlp(const float* __restrict__ gsum, const int* __restrict__ batch,
                      const int* __restrict__ flagp, int N,
                      const float* __restrict__ W1, const float* __restrict__ b1,
                      const float* __restrict__ W2, const float* __restrict__ b2,
                      float* __restrict__ out, int OUTD) {
    int gg = blockIdx.x, c = threadIdx.x;  // 64 threads
    const int f = *flagp;
    int lo = lower_bound_i(batch, N, gg, f);
    int hi = lower_bound_i(batch, N, gg + 1, f);
    float cnt = (float)(hi - lo);
    __shared__ float gs[HID];
    __shared__ float s1[HID];
    gs[c] = gsum[gg * HID + c] / fmaxf(cnt, 1.f);
    __syncthreads();
    float acc = b1[c];
#pragma unroll
    for (int k = 0; k < HID; ++k) acc += gs[k] * W1[k * HID + c];
    s1[c] = fmaxf(acc, 0.f);
    __syncthreads();
    if (c < OUTD) {
        float o = b2[c];
#pragma unroll
        for (int k = 0; k < HID; ++k) o += s1[k] * W2[k * OUTD + c];
        out[gg * OUTD + c] = o;
    }
}

extern "C" void kernel_launch(void* const* d_in, const int* in_sizes, int n_in,
                              void* d_out, int out_size, void* d_ws, size_t ws_size,
                              hipStream_t stream) {
    const float* x       = (const float*)d_in[0];
    const int*   ei_raw  = (const int*)d_in[1];
    const int*   b_raw   = (const int*)d_in[2];
    const float* in_W    = (const float*)d_in[3];
    const float* in_b    = (const float*)d_in[4];
    const float* gat_W   = (const float*)d_in[5];
    const float* att_src = (const float*)d_in[6];
    const float* att_dst = (const float*)d_in[7];
    const float* gat_b   = (const float*)d_in[8];
    const float* bn_g    = (const float*)d_in[9];
    const float* bn_b    = (const float*)d_in[10];
    const float* bn_m    = (const float*)d_in[11];
    const float* bn_v    = (const float*)d_in[12];
    const float* fc1_W   = (const float*)d_in[13];
    const float* fc1_b   = (const float*)d_in[14];
    const float* fc2_W   = (const float*)d_in[15];
    const float* fc2_b   = (const float*)d_in[16];

    const int N = in_sizes[2];          // n_nodes (batch length)
    const int E = in_sizes[1] / 2;      // edges
    const int Etot = E + N;             // + self loops
    const int OUTD = 4;
    const int G = out_size / OUTD;

    // workspace layout (floats), ~53.7 MB total for N=50k
    float* ws = (float*)d_ws;
    float* h     = ws;                           // N*64
    float* ssrc  = h    + (size_t)N * HID;       // N*4
    float* sdst  = ssrc + (size_t)N * HEADS;     // N*4
    float* denom = sdst + (size_t)N * HEADS;     // N*4
    float* aggr  = denom+ (size_t)N * HEADS;     // N*64 (contiguous with denom)
    float* gsum  = aggr + (size_t)N * HID;       // G*64
    int*   flag  = (int*)(gsum + (size_t)G * HID); // 1
    __half* xt   = (__half*)(flag + 2);          // N*256 halves

    k_detect64<<<1, 64, 0, stream>>>(ei_raw, flag);

    k_input<<<N, HID, 0, stream>>>(x, in_W, in_b, h, N);

    for (int l = 0; l < 3; ++l) {
        k_gat_xt<<<(N + NPB - 1) / NPB, 256, 0, stream>>>(
            h, gat_W + (size_t)l * HID * HC, att_src + (size_t)l * HEADS * HID,
            att_dst + (size_t)l * HEADS * HID, xt, ssrc, sdst, N);
        int zn = N * HEADS + N * HID;  // denom + aggr (contiguous)
        k_zero<<<(zn + 255) / 256, 256, 0, stream>>>(denom, zn);
        k_denom<<<(Etot * HEADS + 255) / 256, 256, 0, stream>>>(ei_raw, flag, ssrc, sdst, denom, E, Etot);
        k_msg<<<(int)(((size_t)Etot * 64 + 255) / 256), 256, 0, stream>>>(
            ei_raw, flag, ssrc, sdst, denom, xt, aggr, E, Etot);
        k_node_update<<<(N * HID + 255) / 256, 256, 0, stream>>>(
            aggr, gat_b + (size_t)l * HID, bn_g + (size_t)l * HID, bn_b + (size_t)l * HID,
            bn_m + (size_t)l * HID, bn_v + (size_t)l * HID, h, N);
    }

    k_zero<<<(G * HID + 255) / 256, 256, 0, stream>>>(gsum, G * HID);
    k_pool_sum<<<(N + NPBK - 1) / NPBK, HID, 0, stream>>>(h, b_raw, flag, gsum, N);
    k_mlp<<<G, HID, 0, stream>>>(gsum, b_raw, flag, N, fc1_W, fc1_b, fc2_W, fc2_b,
                                 (float*)d_out, OUTD);
}

// Round 4
// 559.687 us; speedup vs baseline: 2.2325x; 1.8596x over previous
//
#include <hip/hip_runtime.h>
#include <hip/hip_fp16.h>
#include <math.h>

#define HID 64
#define HEADS 4
#define HC (HEADS * HID)   // 256
#define IN_DIM 32
#define NEG 0.2f
#define BN_EPS 1e-5f
#define SCAN_B 256

// ---------- index dtype detection ----------
__global__ void k_detect64(const int* __restrict__ ei, int* __restrict__ flag) {
    if (blockIdx.x == 0 && threadIdx.x == 0) {
        int z = 1;
#pragma unroll
        for (int i = 1; i < 64; i += 2) z &= (ei[i] == 0);
        *flag = z;
    }
}

__device__ __forceinline__ int ld_idx(const int* __restrict__ p, int i, int f64) {
    return f64 ? p[(size_t)2 * i] : p[i];
}

__global__ void k_zero(float* __restrict__ p, int n) {
    int i = blockIdx.x * blockDim.x + threadIdx.x;
    if (i < n) p[i] = 0.f;
}
__global__ void k_zeroi(int* __restrict__ p, int n) {
    int i = blockIdx.x * blockDim.x + threadIdx.x;
    if (i < n) p[i] = 0;
}

// ---------- CSR build: count / scan / scatter ----------
__global__ void k_count(const int* __restrict__ ei, const int* __restrict__ flagp,
                        int* __restrict__ count, int E, int Etot) {
    int e = blockIdx.x * blockDim.x + threadIdx.x;
    if (e >= Etot) return;
    const int f = *flagp;
    int d = (e < E) ? ld_idx(ei, E + e, f) : e - E;
    atomicAdd(&count[d], 1);
}

// per-256-block exclusive scan; block totals -> part[]
__global__ void k_scan1(const int* __restrict__ in, int* __restrict__ out,
                        int* __restrict__ part, int n) {
    __shared__ int tmp[SCAN_B];
    int t = threadIdx.x;
    int i = blockIdx.x * SCAN_B + t;
    int v = (i < n) ? in[i] : 0;
    tmp[t] = v;
    __syncthreads();
    for (int off = 1; off < SCAN_B; off <<= 1) {
        int x = (t >= off) ? tmp[t - off] : 0;
        __syncthreads();
        tmp[t] += x;
        __syncthreads();
    }
    if (i < n) out[i] = tmp[t] - v;  // exclusive
    if (t == SCAN_B - 1) part[blockIdx.x] = tmp[t];
}

// single-block exclusive scan of part[nb] (nb can exceed SCAN_B; chunked)
__global__ void k_scan2(int* __restrict__ part, int nb) {
    __shared__ int tmp[SCAN_B];
    __shared__ int carry_s;
    int t = threadIdx.x;
    if (t == 0) carry_s = 0;
    __syncthreads();
    for (int b = 0; b < nb; b += SCAN_B) {
        int carry = carry_s;
        int v = (b + t < nb) ? part[b + t] : 0;
        tmp[t] = v;
        __syncthreads();
        for (int off = 1; off < SCAN_B; off <<= 1) {
            int x = (t >= off) ? tmp[t - off] : 0;
            __syncthreads();
            tmp[t] += x;
            __syncthreads();
        }
        if (b + t < nb) part[b + t] = tmp[t] - v + carry;
        if (t == SCAN_B - 1) carry_s = carry + tmp[t];
        __syncthreads();
    }
}

__global__ void k_scan3(const int* __restrict__ scanned, const int* __restrict__ part,
                        int* __restrict__ row_ptr, int* __restrict__ cursor,
                        int n, int total) {
    int i = blockIdx.x * blockDim.x + threadIdx.x;
    if (i < n) {
        int v = scanned[i] + part[i / SCAN_B];
        row_ptr[i] = v;
        cursor[i] = v;
    }
    if (i == 0) row_ptr[n] = total;
}

__global__ void k_scatter(const int* __restrict__ ei, const int* __restrict__ flagp,
                          int* __restrict__ cursor, int* __restrict__ src_sorted,
                          int E, int Etot) {
    int e = blockIdx.x * blockDim.x + threadIdx.x;
    if (e >= Etot) return;
    const int f = *flagp;
    int s, d;
    if (e < E) { s = ld_idx(ei, e, f); d = ld_idx(ei, E + e, f); }
    else       { s = d = e - E; }
    int pos = atomicAdd(&cursor[d], 1);
    src_sorted[pos] = s;
}

// ---------- h = x @ in_W + in_b ----------
__global__ void k_input(const float* __restrict__ x, const float* __restrict__ W,
                        const float* __restrict__ b, float* __restrict__ h, int N) {
    int n = blockIdx.x;
    int c = threadIdx.x;  // 0..63
    __shared__ float xs[IN_DIM];
    if (c < IN_DIM) xs[c] = x[n * IN_DIM + c];
    __syncthreads();
    float acc = b[c];
#pragma unroll
    for (int k = 0; k < IN_DIM; ++k) acc += xs[k] * W[k * HID + c];
    h[(size_t)n * HID + c] = acc;
}

// ---------- per-layer: xt = h @ W (reshape [N,4,64]) + attention scores ----------
#define NPB 8
__global__ void k_gat_xt(const float* __restrict__ h, const float* __restrict__ W,
                         const float* __restrict__ asrc, const float* __restrict__ adst,
                         __half* __restrict__ xt, float* __restrict__ ssrc,
                         float* __restrict__ sdst, int N) {
    int t = threadIdx.x;           // 0..255
    int head = t >> 6, lane = t & 63;
    int n0 = blockIdx.x * NPB;
    __shared__ float hs[NPB][HID];
    for (int idx = t; idx < NPB * HID; idx += 256) {
        int j = idx / HID, k = idx % HID;
        int n = n0 + j;
        hs[j][k] = (n < N) ? h[(size_t)n * HID + k] : 0.f;
    }
    __syncthreads();
    float acc[NPB];
#pragma unroll
    for (int j = 0; j < NPB; ++j) acc[j] = 0.f;
    for (int k = 0; k < HID; ++k) {
        float w = W[k * HC + t];
#pragma unroll
        for (int j = 0; j < NPB; ++j) acc[j] += hs[j][k] * w;
    }
    float as = asrc[head * HID + lane];
    float ad = adst[head * HID + lane];
#pragma unroll
    for (int j = 0; j < NPB; ++j) {
        int n = n0 + j;
        if (n >= N) break;
        xt[(size_t)n * HC + t] = __float2half(acc[j]);
        float vs = acc[j] * as;
        float vd = acc[j] * ad;
#pragma unroll
        for (int m = 32; m >= 1; m >>= 1) {
            vs += __shfl_xor(vs, m, 64);
            vd += __shfl_xor(vd, m, 64);
        }
        if (lane == 0) {
            ssrc[(size_t)n * HEADS + head] = vs;
            sdst[(size_t)n * HEADS + head] = vd;
        }
    }
}

// ---------- fused aggregation + softmax + bias/BN/relu/residual ----------
// One wave per dst node. Lane layout: head hh = lane>>4 owns 16 lanes;
// lane loads xt[s][4*lane .. 4*lane+3] (8 B). Single pass accumulates
// numerator (per-lane, 4 channels of its head) and denominator (redundant
// within each 16-lane head group). Softmax divide at the end, then 2x
// shfl_xor folds the 4 head groups; lanes 0..15 write 4 channels each.
__global__ void k_aggr(const int* __restrict__ row_ptr, const int* __restrict__ src_sorted,
                       const float* __restrict__ ssrc, const float* __restrict__ sdst,
                       const __half* __restrict__ xt,
                       const float* __restrict__ gb, const float* __restrict__ bg,
                       const float* __restrict__ bb, const float* __restrict__ bm,
                       const float* __restrict__ bv, float* __restrict__ h, int N) {
    int wid = blockIdx.x * 4 + (threadIdx.x >> 6);
    int lane = threadIdx.x & 63;
    if (wid >= N) return;
    const int d = wid;
    const int lo = row_ptr[d], hi = row_ptr[d + 1];
    const int hh = lane >> 4;
    const float sd = sdst[d * HEADS + hh];
    float den = 0.f;
    float acc0 = 0.f, acc1 = 0.f, acc2 = 0.f, acc3 = 0.f;
    for (int base = lo; base < hi; base += 64) {
        int nb = min(64, hi - base);
        int se = (base + lane < hi) ? src_sorted[base + lane] : 0;
        for (int j = 0; j < nb; ++j) {
            int s = __shfl(se, j, 64);
            float v = ssrc[s * HEADS + hh] + sd;
            v = v > 0.f ? v : NEG * v;
            float ex = __expf(v);
            den += ex;
            float2 rw = *((const float2*)(xt + (size_t)s * HC) + lane);
            __half2 p01 = *(__half2*)&rw.x;
            __half2 p23 = *(__half2*)&rw.y;
            float2 f01 = __half22float2(p01);
            float2 f23 = __half22float2(p23);
            acc0 += ex * f01.x;
            acc1 += ex * f01.y;
            acc2 += ex * f23.x;
            acc3 += ex * f23.y;
        }
    }
    float inv = 1.f / den;  // den > 0 guaranteed (self-loop)
    acc0 *= inv; acc1 *= inv; acc2 *= inv; acc3 *= inv;
    acc0 += __shfl_xor(acc0, 16, 64); acc0 += __shfl_xor(acc0, 32, 64);
    acc1 += __shfl_xor(acc1, 16, 64); acc1 += __shfl_xor(acc1, 32, 64);
    acc2 += __shfl_xor(acc2, 16, 64); acc2 += __shfl_xor(acc2, 32, 64);
    acc3 += __shfl_xor(acc3, 16, 64); acc3 += __shfl_xor(acc3, 32, 64);
    if (lane < 16) {
        int c0 = lane * 4;
        float4 r = ((const float4*)(h + (size_t)d * HID))[lane];
        float4 o;
        {
            float v = 0.25f * acc0 + gb[c0 + 0];
            v = (v - bm[c0 + 0]) * rsqrtf(bv[c0 + 0] + BN_EPS) * bg[c0 + 0] + bb[c0 + 0];
            o.x = fmaxf(v, 0.f) + r.x;
        }
        {
            float v = 0.25f * acc1 + gb[c0 + 1];
            v = (v - bm[c0 + 1]) * rsqrtf(bv[c0 + 1] + BN_EPS) * bg[c0 + 1] + bb[c0 + 1];
            o.y = fmaxf(v, 0.f) + r.y;
        }
        {
            float v = 0.25f * acc2 + gb[c0 + 2];
            v = (v - bm[c0 + 2]) * rsqrtf(bv[c0 + 2] + BN_EPS) * bg[c0 + 2] + bb[c0 + 2];
            o.z = fmaxf(v, 0.f) + r.z;
        }
        {
            float v = 0.25f * acc3 + gb[c0 + 3];
            v = (v - bm[c0 + 3]) * rsqrtf(bv[c0 + 3] + BN_EPS) * bg[c0 + 3] + bb[c0 + 3];
            o.w = fmaxf(v, 0.f) + r.w;
        }
        ((float4*)(h + (size_t)d * HID))[lane] = o;
    }
}

// ---------- global mean pool: node-parallel partial sums ----------
#define NPBK 64
__global__ void k_pool_sum(const float* __restrict__ h, const int* __restrict__ batch,
                           const int* __restrict__ flagp, float* __restrict__ gsum, int N) {
    const int f = *flagp;
    int c = threadIdx.x;  // 0..63
    int n0 = blockIdx.x * NPBK;
    int n1 = min(n0 + NPBK, N);
    if (n0 >= N) return;
    int cur = ld_idx(batch, n0, f);
    float s = 0.f;
    for (int n = n0; n < n1; ++n) {
        int g = ld_idx(batch, n, f);
        if (g != cur) {
            atomicAdd(&gsum[cur * HID + c], s);
            s = 0.f;
            cur = g;
        }
        s += h[(size_t)n * HID + c];
    }
    atomicAdd(&gsum[cur * HID + c], s);
}

__device__ __forceinline__ int lower_bound_i(const int* __restrict__ a, int n, int v, int f) {
    int lo = 0, hi = n;
    while (lo < hi) {
        int mid = (lo + hi) >> 1;
        if (ld_idx(a, mid, f) < v) lo = mid + 1; else hi = mid;
    }
    return lo;
}

// ---------- final MLP head (mean-divide fused in) ----------
__global__ void k_mlp(const float* __restrict__ gsum, const int* __restrict__ batch,
                      const int* __restrict__ flagp, int N,
                      const float* __restrict__ W1, const float* __restrict__ b1,
                      const float* __restrict__ W2, const float* __restrict__ b2,
                      float* __restrict__ out, int OUTD) {
    int gg = blockIdx.x, c = threadIdx.x;  // 64 threads
    const int f = *flagp;
    int lo = lower_bound_i(batch, N, gg, f);
    int hi = lower_bound_i(batch, N, gg + 1, f);
    float cnt = (float)(hi - lo);
    __shared__ float gs[HID];
    __shared__ float s1[HID];
    gs[c] = gsum[gg * HID + c] / fmaxf(cnt, 1.f);
    __syncthreads();
    float acc = b1[c];
#pragma unroll
    for (int k = 0; k < HID; ++k) acc += gs[k] * W1[k * HID + c];
    s1[c] = fmaxf(acc, 0.f);
    __syncthreads();
    if (c < OUTD) {
        float o = b2[c];
#pragma unroll
        for (int k = 0; k < HID; ++k) o += s1[k] * W2[k * OUTD + c];
        out[gg * OUTD + c] = o;
    }
}

extern "C" void kernel_launch(void* const* d_in, const int* in_sizes, int n_in,
                              void* d_out, int out_size, void* d_ws, size_t ws_size,
                              hipStream_t stream) {
    const float* x       = (const float*)d_in[0];
    const int*   ei_raw  = (const int*)d_in[1];
    const int*   b_raw   = (const int*)d_in[2];
    const float* in_W    = (const float*)d_in[3];
    const float* in_b    = (const float*)d_in[4];
    const float* gat_W   = (const float*)d_in[5];
    const float* att_src = (const float*)d_in[6];
    const float* att_dst = (const float*)d_in[7];
    const float* gat_b   = (const float*)d_in[8];
    const float* bn_g    = (const float*)d_in[9];
    const float* bn_b    = (const float*)d_in[10];
    const float* bn_m    = (const float*)d_in[11];
    const float* bn_v    = (const float*)d_in[12];
    const float* fc1_W   = (const float*)d_in[13];
    const float* fc1_b   = (const float*)d_in[14];
    const float* fc2_W   = (const float*)d_in[15];
    const float* fc2_b   = (const float*)d_in[16];

    const int N = in_sizes[2];          // n_nodes
    const int E = in_sizes[1] / 2;      // edges
    const int Etot = E + N;             // + self loops
    const int OUTD = 4;
    const int G = out_size / OUTD;
    const int nb1 = (N + SCAN_B - 1) / SCAN_B;

    // ---- workspace layout (xt first for 512B alignment) ----
    __half* xt   = (__half*)d_ws;                        // N*256 halves (25.6 MB)
    float* h     = (float*)(xt + (size_t)N * HC);        // N*64
    float* ssrc  = h    + (size_t)N * HID;               // N*4
    float* sdst  = ssrc + (size_t)N * HEADS;             // N*4
    float* gsum  = sdst + (size_t)N * HEADS;             // G*64
    int*   flag    = (int*)(gsum + (size_t)G * HID);     // 1 (+pad)
    int*   count   = flag + 4;                           // N
    int*   scanned = count + N;                          // N
    int*   part    = scanned + N;                        // nb1 (+pad)
    int*   row_ptr = part + ((nb1 + 63) & ~63);          // N+1
    int*   cursor  = row_ptr + N + 1;                    // N
    int*   src_sorted = cursor + N;                      // Etot

    k_detect64<<<1, 64, 0, stream>>>(ei_raw, flag);

    // ---- CSR build (once, reused for 3 layers) ----
    k_zeroi<<<(N + 255) / 256, 256, 0, stream>>>(count, N);
    k_count<<<(Etot + 255) / 256, 256, 0, stream>>>(ei_raw, flag, count, E, Etot);
    k_scan1<<<nb1, SCAN_B, 0, stream>>>(count, scanned, part, N);
    k_scan2<<<1, SCAN_B, 0, stream>>>(part, nb1);
    k_scan3<<<(N + 255) / 256, 256, 0, stream>>>(scanned, part, row_ptr, cursor, N, Etot);
    k_scatter<<<(Etot + 255) / 256, 256, 0, stream>>>(ei_raw, flag, cursor, src_sorted, E, Etot);

    k_input<<<N, HID, 0, stream>>>(x, in_W, in_b, h, N);

    for (int l = 0; l < 3; ++l) {
        k_gat_xt<<<(N + NPB - 1) / NPB, 256, 0, stream>>>(
            h, gat_W + (size_t)l * HID * HC, att_src + (size_t)l * HEADS * HID,
            att_dst + (size_t)l * HEADS * HID, xt, ssrc, sdst, N);
        k_aggr<<<(N + 3) / 4, 256, 0, stream>>>(
            row_ptr, src_sorted, ssrc, sdst, xt,
            gat_b + (size_t)l * HID, bn_g + (size_t)l * HID, bn_b + (size_t)l * HID,
            bn_m + (size_t)l * HID, bn_v + (size_t)l * HID, h, N);
    }

    k_zero<<<(G * HID + 255) / 256, 256, 0, stream>>>(gsum, G * HID);
    k_pool_sum<<<(N + NPBK - 1) / NPBK, HID, 0, stream>>>(h, b_raw, flag, gsum, N);
    k_mlp<<<G, HID, 0, stream>>>(gsum, b_raw, flag, N, fc1_W, fc1_b, fc2_W, fc2_b,
                                 (float*)d_out, OUTD);
}